// Round 1
// baseline (4602.788 us; speedup 1.0000x reference)
//
#include <hip/hip_runtime.h>
#include <math.h>

#define B 2048
#define H 256
#define INDIM 320
#define NOPS 1883
#define STEPS 20

#define BM 64
#define BN 64
#define BK 16

// ---------------- init: x = concat(geo, sem); h0 = h1 = 0 ----------------
__global__ __launch_bounds__(256) void init_kernel(const float* __restrict__ geo,
                                                   const float* __restrict__ sem,
                                                   float* __restrict__ x,
                                                   float* __restrict__ h0,
                                                   float* __restrict__ h1) {
    int i = blockIdx.x * blockDim.x + threadIdx.x;
    if (i < B * INDIM) {
        int b = i / INDIM, c = i % INDIM;
        x[i] = (c < 256) ? geo[b * 256 + c] : sem[b * 64 + (c - 256)];
    }
    if (i < B * H) { h0[i] = 0.0f; h1[i] = 0.0f; }
}

// ---------------- generic tiled GEMM: C(M,N) = A(M,K) @ Bm(N,K)^T + bias ----------------
__global__ __launch_bounds__(256) void gemm_tn(const float* __restrict__ A,
                                               const float* __restrict__ Bm,
                                               const float* __restrict__ bias,
                                               float* __restrict__ C,
                                               int M, int N, int K) {
    __shared__ float As[BK][BM];
    __shared__ float Bs[BK][BN];
    int tid = threadIdx.x;
    int bm0 = blockIdx.y * BM;
    int bn0 = blockIdx.x * BN;
    int tx = tid & 15, ty = tid >> 4;
    int lr = tid >> 2;            // 0..63: tile row for loading
    int lk = (tid & 3) << 2;      // 0,4,8,12

    float acc[4][4];
#pragma unroll
    for (int i = 0; i < 4; ++i)
#pragma unroll
        for (int j = 0; j < 4; ++j) acc[i][j] = 0.0f;

    for (int k0 = 0; k0 < K; k0 += BK) {
        {
            int gr = bm0 + lr;
            float4 v = make_float4(0.f, 0.f, 0.f, 0.f);
            if (gr < M) v = *(const float4*)(A + (size_t)gr * K + k0 + lk);
            As[lk + 0][lr] = v.x; As[lk + 1][lr] = v.y;
            As[lk + 2][lr] = v.z; As[lk + 3][lr] = v.w;
        }
        {
            int gn = bn0 + lr;
            float4 v = make_float4(0.f, 0.f, 0.f, 0.f);
            if (gn < N) v = *(const float4*)(Bm + (size_t)gn * K + k0 + lk);
            Bs[lk + 0][lr] = v.x; Bs[lk + 1][lr] = v.y;
            Bs[lk + 2][lr] = v.z; Bs[lk + 3][lr] = v.w;
        }
        __syncthreads();
#pragma unroll
        for (int k = 0; k < BK; ++k) {
            float a[4], b[4];
#pragma unroll
            for (int i = 0; i < 4; ++i) a[i] = As[k][ty * 4 + i];
#pragma unroll
            for (int j = 0; j < 4; ++j) b[j] = Bs[k][tx * 4 + j];
#pragma unroll
            for (int i = 0; i < 4; ++i)
#pragma unroll
                for (int j = 0; j < 4; ++j) acc[i][j] = fmaf(a[i], b[j], acc[i][j]);
        }
        __syncthreads();
    }
#pragma unroll
    for (int i = 0; i < 4; ++i) {
        int gr = bm0 + ty * 4 + i;
        if (gr >= M) continue;
#pragma unroll
        for (int j = 0; j < 4; ++j) {
            int gc = bn0 + tx * 4 + j;
            if (gc < N) C[(size_t)gr * N + gc] = acc[i][j] + (bias ? bias[gc] : 0.0f);
        }
    }
}

// ---------------- GRU gate combine (in-place h update) ----------------
__global__ __launch_bounds__(256) void gru_gate_kernel(const float* __restrict__ gi,
                                                       const float* __restrict__ gh,
                                                       float* __restrict__ h) {
    int i = blockIdx.x * blockDim.x + threadIdx.x;
    if (i >= B * H) return;
    int b = i >> 8;      // /256
    int j = i & 255;
    const float* gib = gi + (size_t)b * 768;
    const float* ghb = gh + (size_t)b * 768;
    float ir = gib[j], iz = gib[j + 256], in = gib[j + 512];
    float hr = ghb[j], hz = ghb[j + 256], hn = ghb[j + 512];
    float r = 1.0f / (1.0f + expf(-(ir + hr)));
    float z = 1.0f / (1.0f + expf(-(iz + hz)));
    float n = tanhf(in + r * hn);
    float hp = h[i];
    h[i] = (1.0f - z) * n + z * hp;
}

// ---------------- per-row squared L2 norm (cols=256) ----------------
__global__ __launch_bounds__(64) void rowsq_kernel(const float* __restrict__ A,
                                                   float* __restrict__ out,
                                                   int cols) {
    int row = blockIdx.x;
    int lane = threadIdx.x;
    const float* r = A + (size_t)row * cols;
    float s = 0.0f;
    for (int c = lane; c < cols; c += 64) { float v = r[c]; s = fmaf(v, v, s); }
#pragma unroll
    for (int off = 32; off > 0; off >>= 1) s += __shfl_down(s, off);
    if (lane == 0) out[row] = s;
}

// ---------------- scores: logits - 0.5*sqrt(||h||^2 + ||opp||^2 - 2 h.opp) ----------------
__global__ __launch_bounds__(256) void scores_kernel(const float* __restrict__ Hm,      // (B,256)
                                                     const float* __restrict__ We,      // (NOPS,256)
                                                     const float* __restrict__ be,      // (NOPS)
                                                     const float* __restrict__ Opp,     // (NOPS,256)
                                                     const float* __restrict__ oppsq,   // (NOPS)
                                                     const float* __restrict__ hsq,     // (B)
                                                     float* __restrict__ out) {         // (B,NOPS)
    __shared__ float As[BK][BM];
    __shared__ float B1s[BK][BN];
    __shared__ float B2s[BK][BN];
    int tid = threadIdx.x;
    int bm0 = blockIdx.y * BM;
    int bn0 = blockIdx.x * BN;
    int tx = tid & 15, ty = tid >> 4;
    int lr = tid >> 2;
    int lk = (tid & 3) << 2;

    float acc1[4][4], acc2[4][4];
#pragma unroll
    for (int i = 0; i < 4; ++i)
#pragma unroll
        for (int j = 0; j < 4; ++j) { acc1[i][j] = 0.0f; acc2[i][j] = 0.0f; }

    for (int k0 = 0; k0 < 256; k0 += BK) {
        {
            float4 v = *(const float4*)(Hm + (size_t)(bm0 + lr) * 256 + k0 + lk);
            As[lk + 0][lr] = v.x; As[lk + 1][lr] = v.y;
            As[lk + 2][lr] = v.z; As[lk + 3][lr] = v.w;
        }
        {
            int gn = bn0 + lr;
            float4 v1 = make_float4(0.f, 0.f, 0.f, 0.f);
            float4 v2 = make_float4(0.f, 0.f, 0.f, 0.f);
            if (gn < NOPS) {
                v1 = *(const float4*)(We + (size_t)gn * 256 + k0 + lk);
                v2 = *(const float4*)(Opp + (size_t)gn * 256 + k0 + lk);
            }
            B1s[lk + 0][lr] = v1.x; B1s[lk + 1][lr] = v1.y;
            B1s[lk + 2][lr] = v1.z; B1s[lk + 3][lr] = v1.w;
            B2s[lk + 0][lr] = v2.x; B2s[lk + 1][lr] = v2.y;
            B2s[lk + 2][lr] = v2.z; B2s[lk + 3][lr] = v2.w;
        }
        __syncthreads();
#pragma unroll
        for (int k = 0; k < BK; ++k) {
            float a[4], b1[4], b2[4];
#pragma unroll
            for (int i = 0; i < 4; ++i) a[i] = As[k][ty * 4 + i];
#pragma unroll
            for (int j = 0; j < 4; ++j) { b1[j] = B1s[k][tx * 4 + j]; b2[j] = B2s[k][tx * 4 + j]; }
#pragma unroll
            for (int i = 0; i < 4; ++i)
#pragma unroll
                for (int j = 0; j < 4; ++j) {
                    acc1[i][j] = fmaf(a[i], b1[j], acc1[i][j]);
                    acc2[i][j] = fmaf(a[i], b2[j], acc2[i][j]);
                }
        }
        __syncthreads();
    }
#pragma unroll
    for (int i = 0; i < 4; ++i) {
        int gr = bm0 + ty * 4 + i;
        float hs = hsq[gr];
#pragma unroll
        for (int j = 0; j < 4; ++j) {
            int gc = bn0 + tx * 4 + j;
            if (gc < NOPS) {
                float logit = acc1[i][j] + be[gc];
                float d2 = hs + oppsq[gc] - 2.0f * acc2[i][j];
                float sc = logit - 0.5f * sqrtf(fmaxf(d2, 0.0f));
                out[(size_t)gr * NOPS + gc] = sc;
            }
        }
    }
}

// ---------------- per-row argmax (first-index tie-break, numpy semantics) ----------------
__global__ __launch_bounds__(256) void argmax_kernel(const float* __restrict__ scores,
                                                     int* __restrict__ sel,
                                                     float* __restrict__ traj) {
    int b = blockIdx.x;
    const float* row = scores + (size_t)b * NOPS;
    float bv = -INFINITY; int bi = 0x7fffffff;
    for (int n = threadIdx.x; n < NOPS; n += 256) {
        float v = row[n];
        if (v > bv) { bv = v; bi = n; }   // increasing n => strict > keeps first
    }
    __shared__ float sv[256];
    __shared__ int si[256];
    sv[threadIdx.x] = bv; si[threadIdx.x] = bi;
    __syncthreads();
    for (int s = 128; s > 0; s >>= 1) {
        if (threadIdx.x < s) {
            float ov = sv[threadIdx.x + s]; int oi = si[threadIdx.x + s];
            if (ov > sv[threadIdx.x] || (ov == sv[threadIdx.x] && oi < si[threadIdx.x])) {
                sv[threadIdx.x] = ov; si[threadIdx.x] = oi;
            }
        }
        __syncthreads();
    }
    if (threadIdx.x == 0) { sel[b] = si[0]; traj[b] = (float)si[0]; }
}

// ---------------- proj: x = [h_top, op_embeds[sel]] @ Wp(320,512)^T + bp ----------------
__global__ __launch_bounds__(256) void proj_kernel(const float* __restrict__ Hm,     // (B,256)
                                                   const float* __restrict__ emb,    // (NOPS,256)
                                                   const int* __restrict__ sel,      // (B)
                                                   const float* __restrict__ Wp,     // (320,512)
                                                   const float* __restrict__ bp,     // (320)
                                                   float* __restrict__ X) {          // (B,320)
    __shared__ float As[BK][BM];
    __shared__ float Bs[BK][BN];
    int tid = threadIdx.x;
    int bm0 = blockIdx.y * BM;
    int bn0 = blockIdx.x * BN;   // N=320, grid.x=5 => always in range
    int tx = tid & 15, ty = tid >> 4;
    int lr = tid >> 2;
    int lk = (tid & 3) << 2;

    float acc[4][4];
#pragma unroll
    for (int i = 0; i < 4; ++i)
#pragma unroll
        for (int j = 0; j < 4; ++j) acc[i][j] = 0.0f;

    for (int k0 = 0; k0 < 512; k0 += BK) {
        {
            int gr = bm0 + lr;
            int kk = k0 + lk;
            const float* src = (kk < 256) ? (Hm + (size_t)gr * 256 + kk)
                                          : (emb + (size_t)sel[gr] * 256 + (kk - 256));
            float4 v = *(const float4*)src;
            As[lk + 0][lr] = v.x; As[lk + 1][lr] = v.y;
            As[lk + 2][lr] = v.z; As[lk + 3][lr] = v.w;
        }
        {
            int gn = bn0 + lr;
            float4 v = *(const float4*)(Wp + (size_t)gn * 512 + k0 + lk);
            Bs[lk + 0][lr] = v.x; Bs[lk + 1][lr] = v.y;
            Bs[lk + 2][lr] = v.z; Bs[lk + 3][lr] = v.w;
        }
        __syncthreads();
#pragma unroll
        for (int k = 0; k < BK; ++k) {
            float a[4], b[4];
#pragma unroll
            for (int i = 0; i < 4; ++i) a[i] = As[k][ty * 4 + i];
#pragma unroll
            for (int j = 0; j < 4; ++j) b[j] = Bs[k][tx * 4 + j];
#pragma unroll
            for (int i = 0; i < 4; ++i)
#pragma unroll
                for (int j = 0; j < 4; ++j) acc[i][j] = fmaf(a[i], b[j], acc[i][j]);
        }
        __syncthreads();
    }
#pragma unroll
    for (int i = 0; i < 4; ++i) {
        int gr = bm0 + ty * 4 + i;
#pragma unroll
        for (int j = 0; j < 4; ++j) {
            int gc = bn0 + tx * 4 + j;
            X[(size_t)gr * 320 + gc] = acc[i][j] + bp[gc];
        }
    }
}

extern "C" void kernel_launch(void* const* d_in, const int* in_sizes, int n_in,
                              void* d_out, int out_size, void* d_ws, size_t ws_size,
                              hipStream_t stream) {
    const float* geo      = (const float*)d_in[0];
    const float* sem      = (const float*)d_in[1];
    const float* w_ih0    = (const float*)d_in[2];
    const float* w_hh0    = (const float*)d_in[3];
    const float* b_ih0    = (const float*)d_in[4];
    const float* b_hh0    = (const float*)d_in[5];
    const float* w_ih1    = (const float*)d_in[6];
    const float* w_hh1    = (const float*)d_in[7];
    const float* b_ih1    = (const float*)d_in[8];
    const float* b_hh1    = (const float*)d_in[9];
    const float* w_energy = (const float*)d_in[10];
    const float* b_energy = (const float*)d_in[11];
    const float* w_proj   = (const float*)d_in[12];
    const float* b_proj   = (const float*)d_in[13];
    const float* w_op     = (const float*)d_in[14];
    const float* op_emb   = (const float*)d_in[15];

    float* ws   = (float*)d_ws;
    float* x    = ws;                               // B*320
    float* h0   = x  + (size_t)B * INDIM;           // B*256
    float* h1   = h0 + (size_t)B * H;               // B*256
    float* gi   = h1 + (size_t)B * H;               // B*768
    float* gh   = gi + (size_t)B * 768;             // B*768
    float* opp  = gh + (size_t)B * 768;             // NOPS*256
    float* oppsq= opp + (size_t)NOPS * 256;         // NOPS
    float* hsq  = oppsq + NOPS;                     // B
    int*   sel  = (int*)(hsq + B);                  // B

    float* out    = (float*)d_out;
    float* traj   = out;                            // STEPS*B (indices as float)
    float* scores = out + (size_t)STEPS * B;        // STEPS*B*NOPS

    // init x, zero hidden states
    init_kernel<<<dim3((B * INDIM + 255) / 256), dim3(256), 0, stream>>>(geo, sem, x, h0, h1);
    // opp = op_embeds @ w_op^T   (NOPS x 256, K=256)
    gemm_tn<<<dim3(256 / BN, (NOPS + BM - 1) / BM), dim3(256), 0, stream>>>(
        op_emb, w_op, nullptr, opp, NOPS, 256, 256);
    rowsq_kernel<<<dim3(NOPS), dim3(64), 0, stream>>>(opp, oppsq, 256);

    for (int t = 0; t < STEPS; ++t) {
        // GRU layer 0
        gemm_tn<<<dim3(768 / BN, B / BM), dim3(256), 0, stream>>>(x,  w_ih0, b_ih0, gi, B, 768, INDIM);
        gemm_tn<<<dim3(768 / BN, B / BM), dim3(256), 0, stream>>>(h0, w_hh0, b_hh0, gh, B, 768, H);
        gru_gate_kernel<<<dim3(B * H / 256), dim3(256), 0, stream>>>(gi, gh, h0);
        // GRU layer 1
        gemm_tn<<<dim3(768 / BN, B / BM), dim3(256), 0, stream>>>(h0, w_ih1, b_ih1, gi, B, 768, H);
        gemm_tn<<<dim3(768 / BN, B / BM), dim3(256), 0, stream>>>(h1, w_hh1, b_hh1, gh, B, 768, H);
        gru_gate_kernel<<<dim3(B * H / 256), dim3(256), 0, stream>>>(gi, gh, h1);
        // scoring
        rowsq_kernel<<<dim3(B), dim3(64), 0, stream>>>(h1, hsq, 256);
        scores_kernel<<<dim3((NOPS + BN - 1) / BN, B / BM), dim3(256), 0, stream>>>(
            h1, w_energy, b_energy, opp, oppsq, hsq, scores + (size_t)t * B * NOPS);
        argmax_kernel<<<dim3(B), dim3(256), 0, stream>>>(
            scores + (size_t)t * B * NOPS, sel, traj + (size_t)t * B);
        // next input
        proj_kernel<<<dim3(320 / BN, B / BM), dim3(256), 0, stream>>>(
            h1, op_emb, sel, w_proj, b_proj, x);
    }
}

// Round 2
// 4432.854 us; speedup vs baseline: 1.0383x; 1.0383x over previous
//
#include <hip/hip_runtime.h>
#include <math.h>

#define B 2048
#define H 256
#define INDIM 320
#define NOPS 1883
#define STEPS 20

// ---------------- init: x = concat(geo, sem); h0a = h1a = 0 ----------------
__global__ __launch_bounds__(256) void init_kernel(const float* __restrict__ geo,
                                                   const float* __restrict__ sem,
                                                   float* __restrict__ x,
                                                   float* __restrict__ h0,
                                                   float* __restrict__ h1) {
    int i = blockIdx.x * blockDim.x + threadIdx.x;
    if (i < B * INDIM) {
        int b = i / INDIM, c = i % INDIM;
        x[i] = (c < 256) ? geo[b * 256 + c] : sem[b * 64 + (c - 256)];
    }
    if (i < B * H) { h0[i] = 0.0f; h1[i] = 0.0f; }
}

// ---------------- generic tiled GEMM (used only for opp precompute) ----------------
#define BM 64
#define BN 64
#define BK 16
__global__ __launch_bounds__(256) void gemm_tn(const float* __restrict__ A,
                                               const float* __restrict__ Bm,
                                               const float* __restrict__ bias,
                                               float* __restrict__ C,
                                               int M, int N, int K) {
    __shared__ float As[BK][BM];
    __shared__ float Bs[BK][BN];
    int tid = threadIdx.x;
    int bm0 = blockIdx.y * BM;
    int bn0 = blockIdx.x * BN;
    int tx = tid & 15, ty = tid >> 4;
    int lr = tid >> 2;
    int lk = (tid & 3) << 2;

    float acc[4][4];
#pragma unroll
    for (int i = 0; i < 4; ++i)
#pragma unroll
        for (int j = 0; j < 4; ++j) acc[i][j] = 0.0f;

    for (int k0 = 0; k0 < K; k0 += BK) {
        {
            int gr = bm0 + lr;
            float4 v = make_float4(0.f, 0.f, 0.f, 0.f);
            if (gr < M) v = *(const float4*)(A + (size_t)gr * K + k0 + lk);
            As[lk + 0][lr] = v.x; As[lk + 1][lr] = v.y;
            As[lk + 2][lr] = v.z; As[lk + 3][lr] = v.w;
        }
        {
            int gn = bn0 + lr;
            float4 v = make_float4(0.f, 0.f, 0.f, 0.f);
            if (gn < N) v = *(const float4*)(Bm + (size_t)gn * K + k0 + lk);
            Bs[lk + 0][lr] = v.x; Bs[lk + 1][lr] = v.y;
            Bs[lk + 2][lr] = v.z; Bs[lk + 3][lr] = v.w;
        }
        __syncthreads();
#pragma unroll
        for (int k = 0; k < BK; ++k) {
            float a[4], b[4];
#pragma unroll
            for (int i = 0; i < 4; ++i) a[i] = As[k][ty * 4 + i];
#pragma unroll
            for (int j = 0; j < 4; ++j) b[j] = Bs[k][tx * 4 + j];
#pragma unroll
            for (int i = 0; i < 4; ++i)
#pragma unroll
                for (int j = 0; j < 4; ++j) acc[i][j] = fmaf(a[i], b[j], acc[i][j]);
        }
        __syncthreads();
    }
#pragma unroll
    for (int i = 0; i < 4; ++i) {
        int gr = bm0 + ty * 4 + i;
        if (gr >= M) continue;
#pragma unroll
        for (int j = 0; j < 4; ++j) {
            int gc = bn0 + tx * 4 + j;
            if (gc < N) C[(size_t)gr * N + gc] = acc[i][j] + (bias ? bias[gc] : 0.0f);
        }
    }
}

// ---------------- per-row squared L2 norm (for opp only) ----------------
__global__ __launch_bounds__(64) void rowsq_kernel(const float* __restrict__ A,
                                                   float* __restrict__ out,
                                                   int cols) {
    int row = blockIdx.x;
    int lane = threadIdx.x;
    const float* r = A + (size_t)row * cols;
    float s = 0.0f;
    for (int c = lane; c < cols; c += 64) { float v = r[c]; s = fmaf(v, v, s); }
#pragma unroll
    for (int off = 32; off > 0; off >>= 1) s += __shfl_down(s, off);
    if (lane == 0) out[row] = s;
}

// ---------------- fused GRU layer ----------------
// Block: 32 batch rows x 64 H cols, all 3 gates, both GEMMs, gate math fused.
// grid = (H/64=4, B/32=64) = 256 blocks, 256 threads.
#define GBK 32

__device__ __forceinline__ void gru_gemm_phase(const float* __restrict__ A, int lda,
                                               const float* __restrict__ W, int ldw,
                                               int r0, int c0, int K,
                                               int tid, int tx, int ty,
                                               float acc[3][2][4],
                                               float (*As)[34], float (*Ws)[196]) {
    for (int k0 = 0; k0 < K; k0 += GBK) {
        // stage A tile: 32 rows x 32 k, [k][row] layout
        {
            int row = tid >> 3;
            int kk = (tid & 7) << 2;
            float4 v = *(const float4*)(A + (size_t)(r0 + row) * lda + k0 + kk);
            As[kk + 0][row] = v.x; As[kk + 1][row] = v.y;
            As[kk + 2][row] = v.z; As[kk + 3][row] = v.w;
        }
        // stage W tile: 192 rows (3 gates x 64 cols) x 32 k, [k][gate*64+col]
#pragma unroll
        for (int it = 0; it < 6; ++it) {
            int flat = tid + 256 * it;
            int wrow = flat >> 3;             // 0..191
            int kk = (flat & 7) << 2;
            int g = wrow >> 6, cc = wrow & 63;
            float4 v = *(const float4*)(W + (size_t)((g << 8) + c0 + cc) * ldw + k0 + kk);
            Ws[kk + 0][wrow] = v.x; Ws[kk + 1][wrow] = v.y;
            Ws[kk + 2][wrow] = v.z; Ws[kk + 3][wrow] = v.w;
        }
        __syncthreads();
#pragma unroll
        for (int k = 0; k < GBK; ++k) {
            float a0 = As[k][(ty << 1) + 0];
            float a1 = As[k][(ty << 1) + 1];
#pragma unroll
            for (int g = 0; g < 3; ++g) {
                const float* wp = &Ws[k][g * 64 + (tx << 2)];
                float4 w = *(const float4*)wp;
                acc[g][0][0] = fmaf(a0, w.x, acc[g][0][0]);
                acc[g][0][1] = fmaf(a0, w.y, acc[g][0][1]);
                acc[g][0][2] = fmaf(a0, w.z, acc[g][0][2]);
                acc[g][0][3] = fmaf(a0, w.w, acc[g][0][3]);
                acc[g][1][0] = fmaf(a1, w.x, acc[g][1][0]);
                acc[g][1][1] = fmaf(a1, w.y, acc[g][1][1]);
                acc[g][1][2] = fmaf(a1, w.z, acc[g][1][2]);
                acc[g][1][3] = fmaf(a1, w.w, acc[g][1][3]);
            }
        }
        __syncthreads();
    }
}

__global__ __launch_bounds__(256) void gru_fused(const float* __restrict__ X, int Kx,
                                                 const float* __restrict__ Hprev,
                                                 const float* __restrict__ Wih,   // (768,Kx)
                                                 const float* __restrict__ Whh,   // (768,256)
                                                 const float* __restrict__ bih,
                                                 const float* __restrict__ bhh,
                                                 float* __restrict__ Hnew) {
    __shared__ float As[GBK][34];
    __shared__ float Ws[GBK][196];
    int tid = threadIdx.x;
    int c0 = blockIdx.x * 64;   // H col base
    int r0 = blockIdx.y * 32;   // batch row base
    int tx = tid & 15;          // cols c0 + tx*4 + j
    int ty = tid >> 4;          // rows r0 + ty*2 + i

    float acc_i[3][2][4];
    float acc_h[3][2][4];
#pragma unroll
    for (int g = 0; g < 3; ++g)
#pragma unroll
        for (int i = 0; i < 2; ++i)
#pragma unroll
            for (int j = 0; j < 4; ++j) { acc_i[g][i][j] = 0.0f; acc_h[g][i][j] = 0.0f; }

    gru_gemm_phase(X, Kx, Wih, Kx, r0, c0, Kx, tid, tx, ty, acc_i, As, Ws);
    gru_gemm_phase(Hprev, 256, Whh, 256, r0, c0, 256, tid, tx, ty, acc_h, As, Ws);

    int cbase = c0 + (tx << 2);
    float br[4], bz[4], bn_i[4], bn_h[4];
#pragma unroll
    for (int j = 0; j < 4; ++j) {
        int c = cbase + j;
        br[j]   = bih[c] + bhh[c];
        bz[j]   = bih[256 + c] + bhh[256 + c];
        bn_i[j] = bih[512 + c];
        bn_h[j] = bhh[512 + c];
    }
#pragma unroll
    for (int i = 0; i < 2; ++i) {
        int r = r0 + (ty << 1) + i;
        float4 hv = *(const float4*)(Hprev + (size_t)r * 256 + cbase);
        float hp[4] = {hv.x, hv.y, hv.z, hv.w};
        float o[4];
#pragma unroll
        for (int j = 0; j < 4; ++j) {
            float rg = 1.0f / (1.0f + expf(-(acc_i[0][i][j] + acc_h[0][i][j] + br[j])));
            float zg = 1.0f / (1.0f + expf(-(acc_i[1][i][j] + acc_h[1][i][j] + bz[j])));
            float ng = tanhf(acc_i[2][i][j] + bn_i[j] + rg * (acc_h[2][i][j] + bn_h[j]));
            o[j] = (1.0f - zg) * ng + zg * hp[j];
        }
        *(float4*)(Hnew + (size_t)r * 256 + cbase) = make_float4(o[0], o[1], o[2], o[3]);
    }
}

// ---------------- fused scores: 128x64 macro, 8x4 micro, dual-B, hsq folded ----------------
// grid = (ceil(NOPS/64)=30, B/128=16) = 480 blocks, 256 threads.
__global__ __launch_bounds__(256) void scores_fused(const float* __restrict__ Hm,    // (B,256)
                                                    const float* __restrict__ We,    // (NOPS,256)
                                                    const float* __restrict__ be,
                                                    const float* __restrict__ Opp,   // (NOPS,256)
                                                    const float* __restrict__ oppsq,
                                                    float* __restrict__ out) {       // (B,NOPS)
    __shared__ float As[32][132];   // [k][row], 128 rows
    __shared__ float B1s[32][68];   // [k][col], 64 cols
    __shared__ float B2s[32][68];
    int tid = threadIdx.x;
    int n0 = blockIdx.x * 64;
    int m0 = blockIdx.y * 128;
    int tx = tid & 15;   // cols n0 + tx*4 + j
    int ty = tid >> 4;   // rows m0 + ty*8 + i

    float acc1[8][4], acc2[8][4], hq[8];
#pragma unroll
    for (int i = 0; i < 8; ++i) {
        hq[i] = 0.0f;
#pragma unroll
        for (int j = 0; j < 4; ++j) { acc1[i][j] = 0.0f; acc2[i][j] = 0.0f; }
    }

    for (int k0 = 0; k0 < 256; k0 += 32) {
#pragma unroll
        for (int it = 0; it < 4; ++it) {
            int flat = tid + 256 * it;
            int row = flat >> 3;            // 0..127
            int kk = (flat & 7) << 2;
            float4 v = *(const float4*)(Hm + (size_t)(m0 + row) * 256 + k0 + kk);
            As[kk + 0][row] = v.x; As[kk + 1][row] = v.y;
            As[kk + 2][row] = v.z; As[kk + 3][row] = v.w;
        }
#pragma unroll
        for (int it = 0; it < 2; ++it) {
            int flat = tid + 256 * it;
            int col = flat >> 3;            // 0..63
            int kk = (flat & 7) << 2;
            int gn = n0 + col;
            float4 v1 = make_float4(0.f, 0.f, 0.f, 0.f);
            float4 v2 = make_float4(0.f, 0.f, 0.f, 0.f);
            if (gn < NOPS) {
                v1 = *(const float4*)(We + (size_t)gn * 256 + k0 + kk);
                v2 = *(const float4*)(Opp + (size_t)gn * 256 + k0 + kk);
            }
            B1s[kk + 0][col] = v1.x; B1s[kk + 1][col] = v1.y;
            B1s[kk + 2][col] = v1.z; B1s[kk + 3][col] = v1.w;
            B2s[kk + 0][col] = v2.x; B2s[kk + 1][col] = v2.y;
            B2s[kk + 2][col] = v2.z; B2s[kk + 3][col] = v2.w;
        }
        __syncthreads();
#pragma unroll
        for (int k = 0; k < 32; ++k) {
            float4 av0 = *(const float4*)&As[k][(ty << 3) + 0];
            float4 av1 = *(const float4*)&As[k][(ty << 3) + 4];
            float a[8] = {av0.x, av0.y, av0.z, av0.w, av1.x, av1.y, av1.z, av1.w};
            float4 b1v = *(const float4*)&B1s[k][tx << 2];
            float4 b2v = *(const float4*)&B2s[k][tx << 2];
            float b1[4] = {b1v.x, b1v.y, b1v.z, b1v.w};
            float b2[4] = {b2v.x, b2v.y, b2v.z, b2v.w};
#pragma unroll
            for (int i = 0; i < 8; ++i) {
                hq[i] = fmaf(a[i], a[i], hq[i]);
#pragma unroll
                for (int j = 0; j < 4; ++j) {
                    acc1[i][j] = fmaf(a[i], b1[j], acc1[i][j]);
                    acc2[i][j] = fmaf(a[i], b2[j], acc2[i][j]);
                }
            }
        }
        __syncthreads();
    }

    float bev[4], osv[4];
#pragma unroll
    for (int j = 0; j < 4; ++j) {
        int n = n0 + (tx << 2) + j;
        bev[j] = (n < NOPS) ? be[n] : 0.0f;
        osv[j] = (n < NOPS) ? oppsq[n] : 0.0f;
    }
#pragma unroll
    for (int i = 0; i < 8; ++i) {
        int m = m0 + (ty << 3) + i;
        float hs = hq[i];
#pragma unroll
        for (int j = 0; j < 4; ++j) {
            int n = n0 + (tx << 2) + j;
            if (n < NOPS) {
                float logit = acc1[i][j] + bev[j];
                float d2 = hs + osv[j] - 2.0f * acc2[i][j];
                out[(size_t)m * NOPS + n] = logit - 0.5f * sqrtf(fmaxf(d2, 0.0f));
            }
        }
    }
}

// ---------------- per-row argmax (first-index tie-break) ----------------
__global__ __launch_bounds__(256) void argmax_kernel(const float* __restrict__ scores,
                                                     int* __restrict__ sel,
                                                     float* __restrict__ traj) {
    int b = blockIdx.x;
    const float* row = scores + (size_t)b * NOPS;
    float bv = -INFINITY; int bi = 0x7fffffff;
    for (int n = threadIdx.x; n < NOPS; n += 256) {
        float v = row[n];
        if (v > bv) { bv = v; bi = n; }
    }
    __shared__ float sv[256];
    __shared__ int si[256];
    sv[threadIdx.x] = bv; si[threadIdx.x] = bi;
    __syncthreads();
    for (int s = 128; s > 0; s >>= 1) {
        if (threadIdx.x < s) {
            float ov = sv[threadIdx.x + s]; int oi = si[threadIdx.x + s];
            if (ov > sv[threadIdx.x] || (ov == sv[threadIdx.x] && oi < si[threadIdx.x])) {
                sv[threadIdx.x] = ov; si[threadIdx.x] = oi;
            }
        }
        __syncthreads();
    }
    if (threadIdx.x == 0) { sel[b] = si[0]; traj[b] = (float)si[0]; }
}

// ---------------- proj: x = [h_top, op_embeds[sel]] @ Wp(320,512)^T + bp ----------------
__global__ __launch_bounds__(256) void proj_kernel(const float* __restrict__ Hm,
                                                   const float* __restrict__ emb,
                                                   const int* __restrict__ sel,
                                                   const float* __restrict__ Wp,
                                                   const float* __restrict__ bp,
                                                   float* __restrict__ X) {
    __shared__ float As[BK][BM];
    __shared__ float Bs[BK][BN];
    int tid = threadIdx.x;
    int bm0 = blockIdx.y * BM;
    int bn0 = blockIdx.x * BN;
    int tx = tid & 15, ty = tid >> 4;
    int lr = tid >> 2;
    int lk = (tid & 3) << 2;

    float acc[4][4];
#pragma unroll
    for (int i = 0; i < 4; ++i)
#pragma unroll
        for (int j = 0; j < 4; ++j) acc[i][j] = 0.0f;

    for (int k0 = 0; k0 < 512; k0 += BK) {
        {
            int gr = bm0 + lr;
            int kk = k0 + lk;
            const float* src = (kk < 256) ? (Hm + (size_t)gr * 256 + kk)
                                          : (emb + (size_t)sel[gr] * 256 + (kk - 256));
            float4 v = *(const float4*)src;
            As[lk + 0][lr] = v.x; As[lk + 1][lr] = v.y;
            As[lk + 2][lr] = v.z; As[lk + 3][lr] = v.w;
        }
        {
            int gn = bn0 + lr;
            float4 v = *(const float4*)(Wp + (size_t)gn * 512 + k0 + lk);
            Bs[lk + 0][lr] = v.x; Bs[lk + 1][lr] = v.y;
            Bs[lk + 2][lr] = v.z; Bs[lk + 3][lr] = v.w;
        }
        __syncthreads();
#pragma unroll
        for (int k = 0; k < BK; ++k) {
            float a[4], b[4];
#pragma unroll
            for (int i = 0; i < 4; ++i) a[i] = As[k][ty * 4 + i];
#pragma unroll
            for (int j = 0; j < 4; ++j) b[j] = Bs[k][tx * 4 + j];
#pragma unroll
            for (int i = 0; i < 4; ++i)
#pragma unroll
                for (int j = 0; j < 4; ++j) acc[i][j] = fmaf(a[i], b[j], acc[i][j]);
        }
        __syncthreads();
    }
#pragma unroll
    for (int i = 0; i < 4; ++i) {
        int gr = bm0 + ty * 4 + i;
#pragma unroll
        for (int j = 0; j < 4; ++j) {
            int gc = bn0 + tx * 4 + j;
            X[(size_t)gr * 320 + gc] = acc[i][j] + bp[gc];
        }
    }
}

extern "C" void kernel_launch(void* const* d_in, const int* in_sizes, int n_in,
                              void* d_out, int out_size, void* d_ws, size_t ws_size,
                              hipStream_t stream) {
    const float* geo      = (const float*)d_in[0];
    const float* sem      = (const float*)d_in[1];
    const float* w_ih0    = (const float*)d_in[2];
    const float* w_hh0    = (const float*)d_in[3];
    const float* b_ih0    = (const float*)d_in[4];
    const float* b_hh0    = (const float*)d_in[5];
    const float* w_ih1    = (const float*)d_in[6];
    const float* w_hh1    = (const float*)d_in[7];
    const float* b_ih1    = (const float*)d_in[8];
    const float* b_hh1    = (const float*)d_in[9];
    const float* w_energy = (const float*)d_in[10];
    const float* b_energy = (const float*)d_in[11];
    const float* w_proj   = (const float*)d_in[12];
    const float* b_proj   = (const float*)d_in[13];
    const float* w_op     = (const float*)d_in[14];
    const float* op_emb   = (const float*)d_in[15];

    float* ws    = (float*)d_ws;
    float* x     = ws;                              // B*320
    float* h0a   = x    + (size_t)B * INDIM;        // B*256
    float* h0b   = h0a  + (size_t)B * H;
    float* h1a   = h0b  + (size_t)B * H;
    float* h1b   = h1a  + (size_t)B * H;
    float* opp   = h1b  + (size_t)B * H;            // NOPS*256
    float* oppsq = opp  + (size_t)NOPS * 256;       // NOPS
    int*   sel   = (int*)(oppsq + NOPS);            // B

    float* out    = (float*)d_out;
    float* traj   = out;                            // STEPS*B
    float* scores = out + (size_t)STEPS * B;        // STEPS*B*NOPS

    init_kernel<<<dim3((B * INDIM + 255) / 256), dim3(256), 0, stream>>>(geo, sem, x, h0a, h1a);
    gemm_tn<<<dim3(256 / BN, (NOPS + BM - 1) / BM), dim3(256), 0, stream>>>(
        op_emb, w_op, nullptr, opp, NOPS, 256, 256);
    rowsq_kernel<<<dim3(NOPS), dim3(64), 0, stream>>>(opp, oppsq, 256);

    for (int t = 0; t < STEPS; ++t) {
        const float* h0_in = (t & 1) ? h0b : h0a;
        float*       h0_out = (t & 1) ? h0a : h0b;
        const float* h1_in = (t & 1) ? h1b : h1a;
        float*       h1_out = (t & 1) ? h1a : h1b;

        gru_fused<<<dim3(H / 64, B / 32), dim3(256), 0, stream>>>(
            x, INDIM, h0_in, w_ih0, w_hh0, b_ih0, b_hh0, h0_out);
        gru_fused<<<dim3(H / 64, B / 32), dim3(256), 0, stream>>>(
            h0_out, H, h1_in, w_ih1, w_hh1, b_ih1, b_hh1, h1_out);

        scores_fused<<<dim3((NOPS + 63) / 64, B / 128), dim3(256), 0, stream>>>(
            h1_out, w_energy, b_energy, opp, oppsq, scores + (size_t)t * B * NOPS);
        argmax_kernel<<<dim3(B), dim3(256), 0, stream>>>(
            scores + (size_t)t * B * NOPS, sel, traj + (size_t)t * B);
        proj_kernel<<<dim3(320 / BN, B / BM), dim3(256), 0, stream>>>(
            h1_out, op_emb, sel, w_proj, b_proj, x);
    }
}